// Round 1
// 644.033 us; speedup vs baseline: 1.0231x; 1.0231x over previous
//
#include <hip/hip_runtime.h>
#include <hip/hip_fp16.h>
#include <stdint.h>

#define T_REL 3
#define F_IN  128
#define F_HID 128
#define F_OUT 64

#define BSHIFT 7                 // 128 dst nodes per bucket
#define BRANGE (1 << BSHIFT)
#define BCAP   3072              // mean 2048, sigma ~45 -> 22 sigma headroom
#define KB_MAX 1024
#define CHUNK_E 4096             // edges per bin block
#define NB_MAX 512

typedef _Float16 f16x8 __attribute__((ext_vector_type(8)));
typedef float    f32x4v __attribute__((ext_vector_type(4)));

// ===========================================================================
// CSR build (unchanged).
// ===========================================================================
__global__ __launch_bounds__(256) void bin_dense_kernel(
    int* __restrict__ bHist, int* __restrict__ lStart, int* __restrict__ colSum,
    uint32_t* __restrict__ binned, const int* __restrict__ edges,
    int E, int KB, int NB)
{
    int t = blockIdx.y, blk = blockIdx.x, tid = threadIdx.x;
    int e0 = blk * CHUNK_E;
    int cnt = min(CHUNK_E, E - e0);

    __shared__ int hist[KB_MAX];
    __shared__ int cursor[KB_MAX];
    __shared__ int sh[256];
    __shared__ uint32_t obuf[CHUNK_E];

    for (int b = tid; b < KB_MAX; b += 256) hist[b] = 0;
    __syncthreads();

    const int* srcA = edges + (size_t)(t * 2) * E;
    const int* dstA = edges + (size_t)(t * 2 + 1) * E;

    uint32_t pk[16]; int bk[16];
#pragma unroll
    for (int r = 0; r < 16; ++r) {
        int i = r * 256 + tid;
        if (i < cnt) {
            int s = srcA[e0 + i], d = dstA[e0 + i];
            bk[r] = d >> BSHIFT;
            pk[r] = ((uint32_t)(d & (BRANGE - 1)) << 17) | (uint32_t)s;
            atomicAdd(&hist[bk[r]], 1);
        } else bk[r] = -1;
    }
    __syncthreads();

    int b4 = tid * 4;
    int v0 = hist[b4], v1 = hist[b4 + 1], v2 = hist[b4 + 2], v3 = hist[b4 + 3];
    sh[tid] = v0 + v1 + v2 + v3;
    __syncthreads();
    for (int off = 1; off < 256; off <<= 1) {
        int x = (tid >= off) ? sh[tid - off] : 0;
        __syncthreads(); sh[tid] += x; __syncthreads();
    }
    int texcl = tid ? sh[tid - 1] : 0;
    cursor[b4] = texcl;
    cursor[b4 + 1] = texcl + v0;
    cursor[b4 + 2] = texcl + v0 + v1;
    cursor[b4 + 3] = texcl + v0 + v1 + v2;
    __syncthreads();

    int* bh = bHist + ((size_t)t * NB + blk) * KB;
    int* ls = lStart + ((size_t)t * NB + blk) * KB;
    for (int b = tid; b < KB; b += 256) {
        int h = hist[b];
        bh[b] = h; ls[b] = cursor[b];
        if (h) atomicAdd(&colSum[t * KB + b], h);
    }
    __syncthreads();

#pragma unroll
    for (int r = 0; r < 16; ++r) {
        if (bk[r] >= 0) {
            int pos = atomicAdd(&cursor[bk[r]], 1);
            obuf[pos] = pk[r];
        }
    }
    __syncthreads();

    for (int i = tid; i < cnt; i += 256)
        binned[(size_t)t * E + e0 + i] = obuf[i];
}

__global__ __launch_bounds__(1024) void bucket_scan_kernel(
    const int* __restrict__ colSum, int* __restrict__ bucketStart,
    int* __restrict__ rp, int KB, int N, int E)
{
    int t = blockIdx.x, tid = threadIdx.x;
    __shared__ int sh[1024];
    int v = (tid < KB) ? colSum[t * KB + tid] : 0;
    sh[tid] = v;
    __syncthreads();
    for (int off = 1; off < 1024; off <<= 1) {
        int x = (tid >= off) ? sh[tid - off] : 0;
        __syncthreads(); sh[tid] += x; __syncthreads();
    }
    if (tid < KB) bucketStart[t * (KB + 1) + tid] = sh[tid] - v;
    if (tid == 0) {
        bucketStart[t * (KB + 1) + KB] = E;
        rp[(size_t)t * (N + 1) + N] = E;
    }
}

__global__ __launch_bounds__(256) void bucket_gather_sort_kernel(
    const int* __restrict__ bHist, const int* __restrict__ lStart,
    const int* __restrict__ bucketStart, const uint32_t* __restrict__ binned,
    int* __restrict__ srcs, int* __restrict__ rp, float* __restrict__ dinv,
    int KB, int NB, int N, int E)
{
    int t = blockIdx.y, b = blockIdx.x, tid = threadIdx.x;
    int base = b << BSHIFT;
    int bstart = bucketStart[t * (KB + 1) + b];

    __shared__ uint32_t eL[BCAP];
    __shared__ int bc[NB_MAX], bo[NB_MAX];
    __shared__ int sh[256];
    __shared__ int hist[BRANGE], excl[BRANGE], cur[BRANGE];

    for (int r = tid; r < NB_MAX; r += 256) bc[r] = 0;
    if (tid < BRANGE) hist[tid] = 0;
    __syncthreads();
    for (int r = tid; r < NB; r += 256)
        bc[r] = bHist[((size_t)t * NB + r) * KB + b];
    __syncthreads();

    int i2 = tid * 2;
    int u0 = bc[i2], u1 = bc[i2 + 1];
    sh[tid] = u0 + u1;
    __syncthreads();
    for (int off = 1; off < 256; off <<= 1) {
        int x = (tid >= off) ? sh[tid - off] : 0;
        __syncthreads(); sh[tid] += x; __syncthreads();
    }
    int te = tid ? sh[tid - 1] : 0;
    bo[i2] = te; bo[i2 + 1] = te + u0;
    __syncthreads();
    int cnt = sh[255]; if (cnt > BCAP) cnt = BCAP;

    for (int r = tid; r < NB; r += 256) {
        int c = bc[r];
        if (!c) continue;
        int off = bo[r];
        const uint32_t* sp = binned + (size_t)t * E + (size_t)r * CHUNK_E
                           + lStart[((size_t)t * NB + r) * KB + b];
        for (int i = 0; i < c; ++i) {
            int p = off + i;
            if (p < BCAP) {
                uint32_t v = sp[i];
                eL[p] = v;
                atomicAdd(&hist[v >> 17], 1);
            }
        }
    }
    __syncthreads();

    if (tid < BRANGE) excl[tid] = hist[tid];
    __syncthreads();
    for (int off = 1; off < BRANGE; off <<= 1) {
        int x = (tid < BRANGE && tid >= off) ? excl[tid - off] : 0;
        __syncthreads();
        if (tid < BRANGE) excl[tid] += x;
        __syncthreads();
    }
    if (tid < BRANGE) {
        int e_ = excl[tid] - hist[tid];
        cur[tid] = e_;
        int g = base + tid;
        if (g < N) {
            rp[(size_t)t * (N + 1) + g] = bstart + e_;
            dinv[(size_t)t * N + g] = rsqrtf(1.0f + (float)hist[tid]);
        }
    }
    __syncthreads();

    int* so = srcs + (size_t)t * E + bstart;
    for (int i = tid; i < cnt; i += 256) {
        uint32_t v = eL[i];
        int slot = atomicAdd(&cur[v >> 17], 1);
        so[slot] = (int)(v & 0x1FFFF);
    }
}

// ===========================================================================
// MFMA fp16 GEMM, fused over relations via blockIdx.y = t:
// H'[t][N x BN] = act(X[N x 128]) @ W[t][128 x BN]  *  dinv[t][row]
// dinv folded into H so the gather inner loop needs no per-edge coefficient.
// ===========================================================================
template<int BN, bool RELU>
__global__ __launch_bounds__(256) void mfma_gemm_kernel(
    const float* __restrict__ X, const float* __restrict__ W,
    __half* __restrict__ H, const float* __restrict__ dinv, int N)
{
    constexpr int BM = 64, K = 128;
    constexpr int XST = K + 8;
    constexpr int WST = K + 8;
    constexpr int LB = (BN == 128) ? 7 : 6;

    __shared__ _Float16 Xs[BM * XST];
    __shared__ _Float16 Ws[BN * WST];

    int tid = threadIdx.x;
    int t   = blockIdx.y;
    int row0 = blockIdx.x * BM;
    const float* Wt  = W + (size_t)t * K * BN;
    const float* dvt = dinv + (size_t)t * N;
    __half*      Ht  = H + (size_t)t * N * BN;

#pragma unroll
    for (int u = 0; u < (BM * K / 4) / 256; ++u) {
        int i = u * 256 + tid;
        int r = i >> 5, c4 = i & 31;
        int gr = row0 + r;
        float4 v = make_float4(0.f, 0.f, 0.f, 0.f);
        if (gr < N) v = reinterpret_cast<const float4*>(X)[(size_t)gr * (K / 4) + c4];
        if (RELU) {
            v.x = fmaxf(v.x, 0.f); v.y = fmaxf(v.y, 0.f);
            v.z = fmaxf(v.z, 0.f); v.w = fmaxf(v.w, 0.f);
        }
        _Float16* xp = &Xs[r * XST + c4 * 4];
        xp[0] = (_Float16)v.x; xp[1] = (_Float16)v.y;
        xp[2] = (_Float16)v.z; xp[3] = (_Float16)v.w;
    }
    for (int idx = tid; idx < K * BN; idx += 256) {
        int k = idx >> LB, n = idx & (BN - 1);
        Ws[n * WST + k] = (_Float16)Wt[idx];
    }
    __syncthreads();

    int wv = tid >> 6, lane = tid & 63, quad = lane >> 4, lr = lane & 15;
    int rw = wv * 16;

    f16x8 a[4];
#pragma unroll
    for (int kk = 0; kk < 4; ++kk)
        a[kk] = *reinterpret_cast<const f16x8*>(&Xs[(rw + lr) * XST + quad * 8 + kk * 32]);

    // per-output-row dinv scale (4 rows handled by this lane across regs)
    float ds[4];
#pragma unroll
    for (int reg = 0; reg < 4; ++reg) {
        int gr = row0 + rw + quad * 4 + reg;
        ds[reg] = (gr < N) ? dvt[gr] : 0.f;
    }

#pragma unroll
    for (int ct = 0; ct < BN / 16; ++ct) {
        f32x4v acc = {0.f, 0.f, 0.f, 0.f};
#pragma unroll
        for (int kk = 0; kk < 4; ++kk) {
            f16x8 bf = *reinterpret_cast<const f16x8*>(&Ws[(ct * 16 + lr) * WST + quad * 8 + kk * 32]);
            acc = __builtin_amdgcn_mfma_f32_16x16x32_f16(a[kk], bf, acc, 0, 0, 0);
        }
#pragma unroll
        for (int reg = 0; reg < 4; ++reg) {
            int gr = row0 + rw + quad * 4 + reg;
            if (gr < N) Ht[(size_t)gr * BN + ct * 16 + lr] = (__half)(acc[reg] * ds[reg]);
        }
    }
}

// ===========================================================================
// Fused CSR gather. dinv[src] is pre-folded into H' by the GEMM epilogue, so
// the inner loop is a pure row-sum:
//   out_t[i] = dinv_t[i] * ( sum_{s in N_t(i)} H'_t[s] + H'_t[i] ) + b_t
// 8-wide edge unroll (two int4 src loads -> 8 independent row loads in
// flight) and 32-bit row offsets (SGPR base + voffset addressing).
// ===========================================================================
template<int F, int NPW>
__global__ __launch_bounds__(256) void gather_fused_kernel(
    float* __restrict__ out, const __half* __restrict__ H,
    const float* __restrict__ dinv, const int* __restrict__ rp,
    const int* __restrict__ srcs, const float* __restrict__ bias,
    int N, int E)
{
    constexpr int LPG = 64 / NPW;
    constexpr int LSH = (LPG == 32) ? 5 : 4;
    static_assert(F == LPG * 4, "4 cols per lane");

    int wave = threadIdx.x >> 6;
    int lane = threadIdx.x & 63;
    int sub  = lane >> LSH;
    int lsub = lane & (LPG - 1);
    int i = (blockIdx.x * 4 + wave) * NPW + sub;
    if (i >= N) return;
    uint32_t c = (uint32_t)lsub * 4;

    float rx = 0.f, ry = 0.f, rz = 0.f, rw_ = 0.f;

    for (int t = 0; t < T_REL; ++t) {
        const __half* Ht = H + (size_t)t * N * F;
        const int*    st = srcs + (size_t)t * E;
        const int*    rpt = rp + (size_t)t * (N + 1);
        float di = dinv[(size_t)t * N + i];

        float ax = 0.f, ay = 0.f, az = 0.f, aw = 0.f;
        auto h4add = [&](float2 raw) {
            __half2 lo = *reinterpret_cast<__half2*>(&raw.x);
            __half2 hi = *reinterpret_cast<__half2*>(&raw.y);
            float2 l = __half22float2(lo), h = __half22float2(hi);
            ax += l.x; ay += l.y; az += h.x; aw += h.y;
        };
        auto rowp = [&](int s) {
            return reinterpret_cast<const float2*>(Ht + ((uint32_t)s * (uint32_t)F + c));
        };

        int beg = rpt[i], end = rpt[i + 1];
        int j = beg;
        int pre = (4 - (beg & 3)) & 3;
        pre = min(pre, end - beg);
        for (int k = 0; k < pre; ++k, ++j) h4add(*rowp(st[j]));

        for (; j + 8 <= end; j += 8) {
            int4 sa = *reinterpret_cast<const int4*>(st + j);
            int4 sb = *reinterpret_cast<const int4*>(st + j + 4);
            float2 r0 = *rowp(sa.x), r1 = *rowp(sa.y);
            float2 r2 = *rowp(sa.z), r3 = *rowp(sa.w);
            float2 r4 = *rowp(sb.x), r5 = *rowp(sb.y);
            float2 r6 = *rowp(sb.z), r7 = *rowp(sb.w);
            h4add(r0); h4add(r1); h4add(r2); h4add(r3);
            h4add(r4); h4add(r5); h4add(r6); h4add(r7);
        }
        if (j + 4 <= end) {
            int4 sa = *reinterpret_cast<const int4*>(st + j);
            float2 r0 = *rowp(sa.x), r1 = *rowp(sa.y);
            float2 r2 = *rowp(sa.z), r3 = *rowp(sa.w);
            h4add(r0); h4add(r1); h4add(r2); h4add(r3);
            j += 4;
        }
        for (; j < end; ++j) h4add(*rowp(st[j]));

        // self loop (H' already carries dinv[i] on the src side)
        h4add(*rowp(i));

        float4 bv = *reinterpret_cast<const float4*>(bias + (size_t)t * F + c);
        rx  += ax * di + bv.x;
        ry  += ay * di + bv.y;
        rz  += az * di + bv.z;
        rw_ += aw * di + bv.w;
    }

    float4 r = make_float4(rx * (1.0f / 3.0f), ry * (1.0f / 3.0f),
                           rz * (1.0f / 3.0f), rw_ * (1.0f / 3.0f));
    *reinterpret_cast<float4*>(out + (size_t)i * F + c) = r;
}

// ===========================================================================
extern "C" void kernel_launch(void* const* d_in, const int* in_sizes, int n_in,
                              void* d_out, int out_size, void* d_ws, size_t ws_size,
                              hipStream_t stream) {
    const float* x     = (const float*)d_in[0];
    const int*   edges = (const int*)  d_in[1];
    const float* W1    = (const float*)d_in[2];
    const float* b1    = (const float*)d_in[3];
    const float* W2    = (const float*)d_in[4];
    const float* b2    = (const float*)d_in[5];
    float* out = (float*)d_out;

    const int N  = in_sizes[0] / F_IN;
    const int E  = in_sizes[1] / (T_REL * 2);
    const int KB = (N + BRANGE - 1) >> BSHIFT;       // 782 buckets/relation
    const int NB = (E + CHUNK_E - 1) / CHUNK_E;      // 391 bin blocks/relation

    auto align256 = [](size_t x_) { return (x_ + 255) & ~(size_t)255; };
    char* p = (char*)d_ws;
    float*  dinv   = (float*)p;  p += align256((size_t)T_REL * N * 4);
    int*    rp     = (int*)p;    p += align256((size_t)T_REL * (N + 1) * 4);
    int*    bstart = (int*)p;    p += align256((size_t)T_REL * (KB + 1) * 4);
    int*    colSum = (int*)p;    p += align256((size_t)T_REL * KB * 4);
    int*    bHist  = (int*)p;    p += align256((size_t)T_REL * NB * KB * 4);
    int*    lStart = (int*)p;    p += align256((size_t)T_REL * NB * KB * 4);
    int*    srcs   = (int*)p;    p += align256((size_t)T_REL * E * 4);
    __half* Hbuf   = (__half*)p; p += align256((size_t)T_REL * N * F_HID * 2);
    float*  h1     = (float*)p;  p += align256((size_t)N * F_HID * 4);
    // binned (19.2 MB) overlays h1 (51.2 MB fp32): binned fully consumed by
    // bucket_gather_sort, which precedes the layer-1 gather that writes h1.
    uint32_t* binned = (uint32_t*)h1;

    // ---- CSR build ----
    hipMemsetAsync(colSum, 0, (size_t)T_REL * KB * sizeof(int), stream);
    {
        dim3 g(NB, T_REL);
        bin_dense_kernel<<<g, 256, 0, stream>>>(bHist, lStart, colSum, binned,
                                                edges, E, KB, NB);
    }
    bucket_scan_kernel<<<T_REL, 1024, 0, stream>>>(colSum, bstart, rp, KB, N, E);
    {
        dim3 g(KB, T_REL);
        bucket_gather_sort_kernel<<<g, 256, 0, stream>>>(
            bHist, lStart, bstart, binned, srcs, rp, dinv, KB, NB, N, E);
    }

    // ---- layer 1: h1 = mean_t( GCNConv(x@W1[t]) + b1[t] ) ----
    {
        dim3 g((N + 63) / 64, T_REL);
        mfma_gemm_kernel<128, false><<<g, 256, 0, stream>>>(x, W1, Hbuf, dinv, N);
    }
    gather_fused_kernel<128, 2><<<(N + 7) / 8, 256, 0, stream>>>(
        h1, Hbuf, dinv, rp, srcs, b1, N, E);

    // ---- layer 2: out = mean_t( GCNConv(relu(h1)@W2[t]) + b2[t] ) ----
    {
        dim3 g((N + 63) / 64, T_REL);
        mfma_gemm_kernel<64, true><<<g, 256, 0, stream>>>(h1, W2, Hbuf, dinv, N);
    }
    gather_fused_kernel<64, 4><<<(N + 15) / 16, 256, 0, stream>>>(
        out, Hbuf, dinv, rp, srcs, b2, N, E);
}

// Round 3
// 612.892 us; speedup vs baseline: 1.0751x; 1.0508x over previous
//
#include <hip/hip_runtime.h>
#include <hip/hip_fp16.h>
#include <stdint.h>

#define T_REL 3
#define F_IN  128
#define F_HID 128
#define F_OUT 64

#define BSHIFT 7                 // 128 dst nodes per bucket
#define BRANGE (1 << BSHIFT)
#define BCAP   3072              // mean 2048, sigma ~45 -> 22 sigma headroom
#define KB_MAX 1024
#define CHUNK_E 4096             // edges per bin block
#define NB_MAX 512
#define PADCAP 520               // per-bucket slack: 128 nodes * 4 + align

typedef _Float16 f16x8 __attribute__((ext_vector_type(8)));
typedef float    f32x4v __attribute__((ext_vector_type(4)));

// ===========================================================================
// CSR build. Segments are padded to a multiple of 4; a self-loop edge (s=i)
// is inserted, and sentinel edges point at row N of H (zeroed by the GEMM).
// ===========================================================================
__global__ __launch_bounds__(256) void bin_dense_kernel(
    int* __restrict__ bHist, int* __restrict__ lStart, int* __restrict__ colSum,
    uint32_t* __restrict__ binned, const int* __restrict__ edges,
    int E, int KB, int NB)
{
    int t = blockIdx.y, blk = blockIdx.x, tid = threadIdx.x;
    int e0 = blk * CHUNK_E;
    int cnt = min(CHUNK_E, E - e0);

    __shared__ int hist[KB_MAX];
    __shared__ int cursor[KB_MAX];
    __shared__ int sh[256];
    __shared__ uint32_t obuf[CHUNK_E];

    for (int b = tid; b < KB_MAX; b += 256) hist[b] = 0;
    __syncthreads();

    const int* srcA = edges + (size_t)(t * 2) * E;
    const int* dstA = edges + (size_t)(t * 2 + 1) * E;

    uint32_t pk[16]; int bk[16];
#pragma unroll
    for (int r = 0; r < 16; ++r) {
        int i = r * 256 + tid;
        if (i < cnt) {
            int s = srcA[e0 + i], d = dstA[e0 + i];
            bk[r] = d >> BSHIFT;
            pk[r] = ((uint32_t)(d & (BRANGE - 1)) << 17) | (uint32_t)s;
            atomicAdd(&hist[bk[r]], 1);
        } else bk[r] = -1;
    }
    __syncthreads();

    int b4 = tid * 4;
    int v0 = hist[b4], v1 = hist[b4 + 1], v2 = hist[b4 + 2], v3 = hist[b4 + 3];
    sh[tid] = v0 + v1 + v2 + v3;
    __syncthreads();
    for (int off = 1; off < 256; off <<= 1) {
        int x = (tid >= off) ? sh[tid - off] : 0;
        __syncthreads(); sh[tid] += x; __syncthreads();
    }
    int texcl = tid ? sh[tid - 1] : 0;
    cursor[b4] = texcl;
    cursor[b4 + 1] = texcl + v0;
    cursor[b4 + 2] = texcl + v0 + v1;
    cursor[b4 + 3] = texcl + v0 + v1 + v2;
    __syncthreads();

    int* bh = bHist + ((size_t)t * NB + blk) * KB;
    int* ls = lStart + ((size_t)t * NB + blk) * KB;
    for (int b = tid; b < KB; b += 256) {
        int h = hist[b];
        bh[b] = h; ls[b] = cursor[b];
        if (h) atomicAdd(&colSum[t * KB + b], h);
    }
    __syncthreads();

#pragma unroll
    for (int r = 0; r < 16; ++r) {
        if (bk[r] >= 0) {
            int pos = atomicAdd(&cursor[bk[r]], 1);
            obuf[pos] = pk[r];
        }
    }
    __syncthreads();

    for (int i = tid; i < cnt; i += 256)
        binned[(size_t)t * E + e0 + i] = obuf[i];
}

// Scan padded bucket capacities: cap_b = align4(colSum) + PADCAP.
__global__ __launch_bounds__(1024) void bucket_scan_kernel(
    const int* __restrict__ colSum, int* __restrict__ bucketStart, int KB)
{
    int t = blockIdx.x, tid = threadIdx.x;
    __shared__ int sh[1024];
    int v = 0;
    if (tid < KB) v = ((colSum[t * KB + tid] + 3) & ~3) + PADCAP;
    sh[tid] = v;
    __syncthreads();
    for (int off = 1; off < 1024; off <<= 1) {
        int x = (tid >= off) ? sh[tid - off] : 0;
        __syncthreads(); sh[tid] += x; __syncthreads();
    }
    if (tid < KB) bucketStart[t * (KB + 1) + tid] = sh[tid] - v;
}

__global__ __launch_bounds__(256) void bucket_gather_sort_kernel(
    const int* __restrict__ bHist, const int* __restrict__ lStart,
    const int* __restrict__ bucketStart, const uint32_t* __restrict__ binned,
    int* __restrict__ srcs, int* __restrict__ rp, int* __restrict__ rpe,
    float* __restrict__ dinv, int KB, int NB, int N, int E, int EP)
{
    int t = blockIdx.y, b = blockIdx.x, tid = threadIdx.x;
    int base = b << BSHIFT;
    int bstart = bucketStart[t * (KB + 1) + b];

    __shared__ uint32_t eL[BCAP];
    __shared__ int bc[NB_MAX], bo[NB_MAX];
    __shared__ int sh[256];
    __shared__ int hist[BRANGE], excl[BRANGE], cur[BRANGE];

    for (int r = tid; r < NB_MAX; r += 256) bc[r] = 0;
    if (tid < BRANGE) hist[tid] = 0;
    __syncthreads();
    for (int r = tid; r < NB; r += 256)
        bc[r] = bHist[((size_t)t * NB + r) * KB + b];
    __syncthreads();

    int i2 = tid * 2;
    int u0 = bc[i2], u1 = bc[i2 + 1];
    sh[tid] = u0 + u1;
    __syncthreads();
    for (int off = 1; off < 256; off <<= 1) {
        int x = (tid >= off) ? sh[tid - off] : 0;
        __syncthreads(); sh[tid] += x; __syncthreads();
    }
    int te = tid ? sh[tid - 1] : 0;
    bo[i2] = te; bo[i2 + 1] = te + u0;
    __syncthreads();
    int cnt = sh[255]; if (cnt > BCAP) cnt = BCAP;

    for (int r = tid; r < NB; r += 256) {
        int c = bc[r];
        if (!c) continue;
        int off = bo[r];
        const uint32_t* sp = binned + (size_t)t * E + (size_t)r * CHUNK_E
                           + lStart[((size_t)t * NB + r) * KB + b];
        for (int i = 0; i < c; ++i) {
            int p = off + i;
            if (p < BCAP) {
                uint32_t v = sp[i];
                eL[p] = v;
                atomicAdd(&hist[v >> 17], 1);
            }
        }
    }
    __syncthreads();

    // scan PADDED per-node sizes: pad = (deg + 1(self) + 3) & ~3
    if (tid < BRANGE) excl[tid] = (hist[tid] + 4) & ~3;
    __syncthreads();
    for (int off = 1; off < BRANGE; off <<= 1) {
        int x = (tid < BRANGE && tid >= off) ? excl[tid - off] : 0;
        __syncthreads();
        if (tid < BRANGE) excl[tid] += x;
        __syncthreads();
    }
    if (tid < BRANGE) {
        int deg = hist[tid];
        int p = (deg + 4) & ~3;
        int e_ = excl[tid] - p;          // exclusive prefix of padded sizes
        cur[tid] = e_;
        int g = base + tid;
        if (g < N) {
            rp [(size_t)t * N + g] = bstart + e_;
            rpe[(size_t)t * N + g] = bstart + e_ + p;
            dinv[(size_t)t * N + g] = rsqrtf(1.0f + (float)deg);
            int* seg = srcs + (size_t)t * EP + bstart + e_;
            seg[deg] = g;                                 // self-loop edge
            for (int k = deg + 1; k < p; ++k) seg[k] = N; // sentinel -> zero row
        }
    }
    __syncthreads();

    int* so = srcs + (size_t)t * EP + bstart;
    for (int i = tid; i < cnt; i += 256) {
        uint32_t v = eL[i];
        int slot = atomicAdd(&cur[v >> 17], 1);
        so[slot] = (int)(v & 0x1FFFF);
    }
}

// ===========================================================================
// MFMA fp16 GEMM: H'[t][(N+1) x BN] = act(X) @ W[t] * dinv[t][row].
// Row N (sentinel target) is written as zeros.
// ===========================================================================
template<int BN, bool RELU>
__global__ __launch_bounds__(256) void mfma_gemm_kernel(
    const float* __restrict__ X, const float* __restrict__ W,
    __half* __restrict__ H, const float* __restrict__ dinv, int N)
{
    constexpr int BM = 64, K = 128;
    constexpr int XST = K + 8;
    constexpr int WST = K + 8;
    constexpr int LB = (BN == 128) ? 7 : 6;

    __shared__ _Float16 Xs[BM * XST];
    __shared__ _Float16 Ws[BN * WST];

    int tid = threadIdx.x;
    int t   = blockIdx.y;
    int row0 = blockIdx.x * BM;
    const float* Wt  = W + (size_t)t * K * BN;
    const float* dvt = dinv + (size_t)t * N;
    __half*      Ht  = H + (size_t)t * (N + 1) * BN;

#pragma unroll
    for (int u = 0; u < (BM * K / 4) / 256; ++u) {
        int i = u * 256 + tid;
        int r = i >> 5, c4 = i & 31;
        int gr = row0 + r;
        float4 v = make_float4(0.f, 0.f, 0.f, 0.f);
        if (gr < N) v = reinterpret_cast<const float4*>(X)[(size_t)gr * (K / 4) + c4];
        if (RELU) {
            v.x = fmaxf(v.x, 0.f); v.y = fmaxf(v.y, 0.f);
            v.z = fmaxf(v.z, 0.f); v.w = fmaxf(v.w, 0.f);
        }
        _Float16* xp = &Xs[r * XST + c4 * 4];
        xp[0] = (_Float16)v.x; xp[1] = (_Float16)v.y;
        xp[2] = (_Float16)v.z; xp[3] = (_Float16)v.w;
    }
    for (int idx = tid; idx < K * BN; idx += 256) {
        int k = idx >> LB, n = idx & (BN - 1);
        Ws[n * WST + k] = (_Float16)Wt[idx];
    }
    __syncthreads();

    int wv = tid >> 6, lane = tid & 63, quad = lane >> 4, lr = lane & 15;
    int rw = wv * 16;

    f16x8 a[4];
#pragma unroll
    for (int kk = 0; kk < 4; ++kk)
        a[kk] = *reinterpret_cast<const f16x8*>(&Xs[(rw + lr) * XST + quad * 8 + kk * 32]);

    float ds[4];
#pragma unroll
    for (int reg = 0; reg < 4; ++reg) {
        int gr = row0 + rw + quad * 4 + reg;
        ds[reg] = (gr < N) ? dvt[gr] : 0.f;   // row N -> 0 (sentinel zero row)
    }

#pragma unroll
    for (int ct = 0; ct < BN / 16; ++ct) {
        f32x4v acc = {0.f, 0.f, 0.f, 0.f};
#pragma unroll
        for (int kk = 0; kk < 4; ++kk) {
            f16x8 bf = *reinterpret_cast<const f16x8*>(&Ws[(ct * 16 + lr) * WST + quad * 8 + kk * 32]);
            acc = __builtin_amdgcn_mfma_f32_16x16x32_f16(a[kk], bf, acc, 0, 0, 0);
        }
#pragma unroll
        for (int reg = 0; reg < 4; ++reg) {
            int gr = row0 + rw + quad * 4 + reg;
            if (gr <= N) Ht[(size_t)gr * BN + ct * 16 + lr] = (__half)(acc[reg] * ds[reg]);
        }
    }
}

// ===========================================================================
// Fused CSR gather, padded/aligned segments, float4 row loads.
// LPR lanes per row (16 for F=128, 8 for F=64), each lane holds 8 halves.
// Self-loop and padding are real edges (sentinel -> zero row N), so the loop
// has no prologue/tail and no per-edge coefficient (dinv folded into H).
//   out[i] = (1/3) * sum_t ( dinv_t[i] * sum_seg H'_t[s] + b_t )
// ===========================================================================
template<int F, int LPR>
__global__ __launch_bounds__(256) void gather_fused_kernel(
    float* __restrict__ out, const __half* __restrict__ H,
    const float* __restrict__ dinv, const int* __restrict__ rp,
    const int* __restrict__ rpe, const int* __restrict__ srcs,
    const float* __restrict__ bias, int N, int EP)
{
    constexpr int NPW = 64 / LPR;
    static_assert(F == LPR * 8, "8 halves per lane");

    int wave = threadIdx.x >> 6;
    int lane = threadIdx.x & 63;
    int sub  = lane / LPR;
    int lcol = lane & (LPR - 1);
    int i = (blockIdx.x * 4 + wave) * NPW + sub;
    if (i >= N) return;
    uint32_t c = (uint32_t)lcol * 8;         // half-index within row

    float r0 = 0.f, r1 = 0.f, r2 = 0.f, r3 = 0.f,
          r4 = 0.f, r5 = 0.f, r6 = 0.f, r7 = 0.f;

    for (int t = 0; t < T_REL; ++t) {
        const __half* Ht = H + (size_t)t * (N + 1) * F;
        const int*    st = srcs + (size_t)t * EP;
        float di = dinv[(size_t)t * N + i];

        float s0 = 0.f, s1 = 0.f, s2 = 0.f, s3 = 0.f,
              s4 = 0.f, s5 = 0.f, s6 = 0.f, s7 = 0.f;

        auto rowld = [&](int s) -> float4 {
            return *reinterpret_cast<const float4*>(Ht + ((uint32_t)s * (uint32_t)F + c));
        };
        auto acc8 = [&](float4 q) {
            const __half2* hp = reinterpret_cast<const __half2*>(&q);
            float2 f0 = __half22float2(hp[0]);
            float2 f1 = __half22float2(hp[1]);
            float2 f2 = __half22float2(hp[2]);
            float2 f3 = __half22float2(hp[3]);
            s0 += f0.x; s1 += f0.y; s2 += f1.x; s3 += f1.y;
            s4 += f2.x; s5 += f2.y; s6 += f3.x; s7 += f3.y;
        };

        int j   = rp [(size_t)t * N + i];
        int end = rpe[(size_t)t * N + i];

        for (; j + 8 <= end; j += 8) {
            int4 pa = *reinterpret_cast<const int4*>(st + j);
            int4 pb = *reinterpret_cast<const int4*>(st + j + 4);
            float4 q0 = rowld(pa.x), q1 = rowld(pa.y), q2 = rowld(pa.z), q3 = rowld(pa.w);
            float4 q4 = rowld(pb.x), q5 = rowld(pb.y), q6 = rowld(pb.z), q7 = rowld(pb.w);
            acc8(q0); acc8(q1); acc8(q2); acc8(q3);
            acc8(q4); acc8(q5); acc8(q6); acc8(q7);
        }
        if (j < end) {                      // exactly one aligned 4-group
            int4 pa = *reinterpret_cast<const int4*>(st + j);
            float4 q0 = rowld(pa.x), q1 = rowld(pa.y), q2 = rowld(pa.z), q3 = rowld(pa.w);
            acc8(q0); acc8(q1); acc8(q2); acc8(q3);
        }

        const float4 b0 = *reinterpret_cast<const float4*>(bias + (size_t)t * F + c);
        const float4 b1 = *reinterpret_cast<const float4*>(bias + (size_t)t * F + c + 4);
        r0 += s0 * di + b0.x; r1 += s1 * di + b0.y;
        r2 += s2 * di + b0.z; r3 += s3 * di + b0.w;
        r4 += s4 * di + b1.x; r5 += s5 * di + b1.y;
        r6 += s6 * di + b1.z; r7 += s7 * di + b1.w;
    }

    constexpr float inv3 = 1.0f / 3.0f;
    float4 o0 = make_float4(r0 * inv3, r1 * inv3, r2 * inv3, r3 * inv3);
    float4 o1 = make_float4(r4 * inv3, r5 * inv3, r6 * inv3, r7 * inv3);
    float* op = out + (size_t)i * F + c;
    *reinterpret_cast<float4*>(op)     = o0;
    *reinterpret_cast<float4*>(op + 4) = o1;
}

// ===========================================================================
extern "C" void kernel_launch(void* const* d_in, const int* in_sizes, int n_in,
                              void* d_out, int out_size, void* d_ws, size_t ws_size,
                              hipStream_t stream) {
    const float* x     = (const float*)d_in[0];
    const int*   edges = (const int*)  d_in[1];
    const float* W1    = (const float*)d_in[2];
    const float* b1    = (const float*)d_in[3];
    const float* W2    = (const float*)d_in[4];
    const float* b2    = (const float*)d_in[5];
    float* out = (float*)d_out;

    const int N  = in_sizes[0] / F_IN;
    const int E  = in_sizes[1] / (T_REL * 2);
    const int KB = (N + BRANGE - 1) >> BSHIFT;       // 782 buckets/relation
    const int NB = (E + CHUNK_E - 1) / CHUNK_E;      // 391 bin blocks/relation
    // per-bucket capacity is align4(colSum_b)+PADCAP; align4 adds up to +3,
    // so total needs E + (PADCAP+3)*KB.  Use +4 slack per bucket.
    const int EP = E + (PADCAP + 4) * KB + 256;

    auto align256 = [](size_t x_) { return (x_ + 255) & ~(size_t)255; };
    char* p = (char*)d_ws;
    float*  dinv   = (float*)p;  p += align256((size_t)T_REL * N * 4);
    int*    rp     = (int*)p;    p += align256((size_t)T_REL * N * 4);
    int*    rpe    = (int*)p;    p += align256((size_t)T_REL * N * 4);
    int*    bstart = (int*)p;    p += align256((size_t)T_REL * (KB + 1) * 4);
    int*    colSum = (int*)p;    p += align256((size_t)T_REL * KB * 4);
    int*    srcs   = (int*)p;    p += align256((size_t)T_REL * EP * 4);
    __half* Hbuf   = (__half*)p; p += align256((size_t)T_REL * (N + 1) * F_HID * 2);
    float*  h1     = (float*)p;  p += align256((size_t)N * F_HID * 4);
    // CSR-build scratch (binned 19.2MB + bHist/lStart 7.3MB) overlays h1
    // (51.2MB): all three are fully consumed by bucket_gather_sort, which
    // precedes the layer-1 gather that writes h1.
    char* q = (char*)h1;
    uint32_t* binned = (uint32_t*)q; q += align256((size_t)T_REL * E * 4);
    int*      bHist  = (int*)q;      q += align256((size_t)T_REL * NB * KB * 4);
    int*      lStart = (int*)q;      q += align256((size_t)T_REL * NB * KB * 4);

    // ---- CSR build ----
    hipMemsetAsync(colSum, 0, (size_t)T_REL * KB * sizeof(int), stream);
    {
        dim3 g(NB, T_REL);
        bin_dense_kernel<<<g, 256, 0, stream>>>(bHist, lStart, colSum, binned,
                                                edges, E, KB, NB);
    }
    bucket_scan_kernel<<<T_REL, 1024, 0, stream>>>(colSum, bstart, KB);
    {
        dim3 g(KB, T_REL);
        bucket_gather_sort_kernel<<<g, 256, 0, stream>>>(
            bHist, lStart, bstart, binned, srcs, rp, rpe, dinv, KB, NB, N, E, EP);
    }

    // ---- layer 1: h1 = mean_t( GCNConv(x@W1[t]) + b1[t] ) ----
    {
        dim3 g(N / 64 + 1, T_REL);   // +1: always cover sentinel row N
        mfma_gemm_kernel<128, false><<<g, 256, 0, stream>>>(x, W1, Hbuf, dinv, N);
    }
    gather_fused_kernel<128, 16><<<(N + 15) / 16, 256, 0, stream>>>(
        h1, Hbuf, dinv, rp, rpe, srcs, b1, N, EP);

    // ---- layer 2: out = mean_t( GCNConv(relu(h1)@W2[t]) + b2[t] ) ----
    {
        dim3 g(N / 64 + 1, T_REL);
        mfma_gemm_kernel<64, true><<<g, 256, 0, stream>>>(h1, W2, Hbuf, dinv, N);
    }
    gather_fused_kernel<64, 8><<<(N + 31) / 32, 256, 0, stream>>>(
        out, Hbuf, dinv, rp, rpe, srcs, b2, N, EP);
}